// Round 1
// baseline (42.222 us; speedup 1.0000x reference)
//
#include <hip/hip_runtime.h>

// Depth-to-space (pixel shuffle), r=4.
// x: [8, 256, 128, 128] f32  ->  y: [8, 16, 512, 512] f32
// y[b, od, H, W] = x[b, od*16 + (H%4)*4 + (W%4), H/4, W/4]
//
// One thread per output float4 (W = 4w .. 4w+3, fixed b/od/H):
//   reads x[b, od*16 + rh*4 + rw, h, w] for rw = 0..3  (4 coalesced scalar loads,
//   stride 128*128 = 16384 floats apart)
//   writes one coalesced float4.

#define HW_IN   (128 * 128)          // per-channel plane, floats
#define W4      128                  // float4s per output row
#define HOUT    512                  // output rows per (b, od)

__global__ __launch_bounds__(256) void d2s_kernel(const float* __restrict__ x,
                                                  float* __restrict__ y) {
    const int tid = blockIdx.x * blockDim.x + threadIdx.x;  // 8,388,608 total

    const int w   = tid & (W4 - 1);        // input w, also output float4 index in row
    const int t1  = tid >> 7;              // (b*16 + od)*512 + H
    const int H   = t1 & (HOUT - 1);
    const int bod = t1 >> 9;               // b*16 + od  (== (b*256 + od*16)/16)

    const int h  = H >> 2;
    const int rh = H & 3;

    // channel base = b*256 + od*16 + rh*4 = bod*16 + rh*4
    const float* __restrict__ src = x + ((size_t)(bod * 16 + rh * 4) * 128 + h) * 128 + w;

    float4 v;
    v.x = src[0 * HW_IN];
    v.y = src[1 * HW_IN];
    v.z = src[2 * HW_IN];
    v.w = src[3 * HW_IN];

    reinterpret_cast<float4*>(y)[tid] = v;
}

extern "C" void kernel_launch(void* const* d_in, const int* in_sizes, int n_in,
                              void* d_out, int out_size, void* d_ws, size_t ws_size,
                              hipStream_t stream) {
    const float* x = (const float*)d_in[0];
    float* y = (float*)d_out;

    // out_size = 8*16*512*512 = 33,554,432 floats -> 8,388,608 float4 threads
    const int n_threads = out_size / 4;
    const int block = 256;
    const int grid = n_threads / block;   // 32768, exact

    d2s_kernel<<<grid, block, 0, stream>>>(x, y);
}